// Round 4
// baseline (691.377 us; speedup 1.0000x reference)
//
#include <hip/hip_runtime.h>

// Memory_Pooling_Layer — MI355X (gfx950)
//
// Key identity: the reference applies softmax over a SINGLETON axis
// (C[:, None, :, :], axis=1), which yields exactly 1.0 everywhere. Hence:
//   new_node_set[b,k,:] = leakyrelu( (sum_n node_set[b,n,:]) @ lin_w + lin_b )   (same for all k)
//   new_adj[b,k,j]      = sum_{n,m} adj[b,n,m]                                   (same for all k,j)
// The centroids / distance / head-softmax pipeline is dead code for the outputs.
// The kernel is therefore HBM-bound on a single read of adj (512 MB).

namespace {

constexpr int kB    = 8;
constexpr int kNIn  = 4096;
constexpr int kDIn  = 128;
constexpr int kNOut = 256;
constexpr int kDOut = 128;
constexpr float kSlope = 0.01f;

// clang ext-vector so __builtin_nontemporal_load accepts the pointer
// (HIP_vector_type<float,4>* is rejected — round-3 compile error).
typedef float v4f __attribute__((ext_vector_type(4)));

// ---- kernel 1: s[b][d] = sum_n node[b,n,d] ------------------------------
// grid (B, 64), block 128. Each block sums 64 rows; coalesced 512B row reads.
__global__ void node_colsum(const float* __restrict__ node, float* __restrict__ s) {
  const int b = blockIdx.x;
  const int chunk = blockIdx.y;       // 64 chunks of 64 rows
  const int d = threadIdx.x;          // 0..127
  const float* p = node + ((size_t)b * kNIn + (size_t)chunk * 64) * kDIn + d;
  float acc = 0.0f;
#pragma unroll
  for (int r = 0; r < 64; ++r) acc += p[(size_t)r * kDIn];
  atomicAdd(&s[b * kDIn + d], acc);
}

// ---- kernel 2: T[b] = sum_{n,m} adj[b,n,m] ------------------------------
// grid (256, B), block 256. v4f grid-stride within batch; double accum.
// Non-temporal loads: adj is read exactly once, keep it out of L2/LLC.
__global__ void adj_sum(const v4f* __restrict__ adj, double* __restrict__ T) {
  const int b = blockIdx.y;
  constexpr int kVec = kNIn * kNIn / 4;      // 4,194,304 v4f per batch
  const int stride = gridDim.x * blockDim.x; // 65536 threads per batch
  const v4f* p = adj + (size_t)b * kVec;
  double acc = 0.0;
  for (int i = blockIdx.x * blockDim.x + threadIdx.x; i < kVec; i += stride) {
    v4f v = __builtin_nontemporal_load(&p[i]);
    acc += (double)((v.x + v.y) + (v.z + v.w));
  }
  // wave-64 butterfly reduce
#pragma unroll
  for (int off = 32; off > 0; off >>= 1) acc += __shfl_down(acc, off);
  __shared__ double part[4];
  const int lane = threadIdx.x & 63;
  const int wv = threadIdx.x >> 6;
  if (lane == 0) part[wv] = acc;
  __syncthreads();
  if (threadIdx.x == 0) {
    atomicAdd(&T[b], (part[0] + part[1]) + (part[2] + part[3]));
  }
}

// ---- kernel 3 (fused epilogue) ------------------------------------------
// grid (B, 32), block 128.
//   y <  16 : out1[b,k,d] = leakyrelu(s[b] @ lin_w + lin_b)[d]; 16 k-rows/block
//   y >= 16 : out2[b,k,j] = (float)T[b]; 1024 float4 per block
__global__ void epilogue(const float* __restrict__ s, const float* __restrict__ lw,
                         const float* __restrict__ lb, const double* __restrict__ T,
                         float* __restrict__ out1, float* __restrict__ out2) {
  const int b = blockIdx.x;
  const int y = blockIdx.y;
  const int d = threadIdx.x;  // 0..127
  if (y < 16) {
    __shared__ float sv[kDIn];
    sv[d] = s[b * kDIn + d];
    __syncthreads();
    float acc = lb[d];
#pragma unroll 16
    for (int i = 0; i < kDIn; ++i) acc = fmaf(sv[i], lw[i * kDOut + d], acc);
    acc = acc >= 0.0f ? acc : kSlope * acc;
    float* dst = out1 + ((size_t)b * kNOut + (size_t)y * 16) * kDOut + d;
#pragma unroll
    for (int k = 0; k < 16; ++k) dst[(size_t)k * kDOut] = acc;
  } else {
    const float t = (float)T[b];
    v4f tv; tv.x = t; tv.y = t; tv.z = t; tv.w = t;
    v4f* dst = (v4f*)(out2 + (size_t)b * kNOut * kNOut);
    const int base = (y - 16) * (kNOut * kNOut / 16 / 4) + d;  // 1024 v4f per block
#pragma unroll
    for (int r = 0; r < 8; ++r) dst[base + r * kDIn] = tv;
  }
}

}  // namespace

extern "C" void kernel_launch(void* const* d_in, const int* in_sizes, int n_in,
                              void* d_out, int out_size, void* d_ws, size_t ws_size,
                              hipStream_t stream) {
  const float* node = (const float*)d_in[0];   // (8, 4096, 128)
  const float* adj  = (const float*)d_in[1];   // (8, 4096, 4096)
  // d_in[2..4] (centroids, conv_w, conv_b) are dead code — see header comment.
  const float* lw   = (const float*)d_in[5];   // (128, 128)
  const float* lb   = (const float*)d_in[6];   // (128,)

  float* out1 = (float*)d_out;                                // 8*256*128
  float* out2 = out1 + (size_t)kB * kNOut * kDOut;            // 8*256*256

  double* T = (double*)d_ws;                                  // 8 doubles
  float*  s = (float*)((char*)d_ws + kB * sizeof(double));    // 8*128 floats

  // zero the accumulators (ws is re-poisoned to 0xAA before every launch)
  (void)hipMemsetAsync(d_ws, 0, kB * sizeof(double) + (size_t)kB * kDIn * sizeof(float), stream);

  node_colsum<<<dim3(kB, kNIn / 64), 128, 0, stream>>>(node, s);
  adj_sum<<<dim3(256, kB), 256, 0, stream>>>((const v4f*)adj, T);
  epilogue<<<dim3(kB, 32), 128, 0, stream>>>(s, lw, lb, T, out1, out2);
}